// Round 1
// 557.423 us; speedup vs baseline: 1.3338x; 1.3338x over previous
//
#include <hip/hip_runtime.h>
#include <cstdint>
#include <cstddef>

typedef _Float16 f16;
typedef _Float16 half8 __attribute__((ext_vector_type(8)));
typedef _Float16 half4 __attribute__((ext_vector_type(4)));
typedef float float4v __attribute__((ext_vector_type(4)));

static __device__ __forceinline__ float4v mfma16(half8 a, half8 b, float4v c) {
  return __builtin_amdgcn_mfma_f32_16x16x32_f16(a, b, c, 0, 0, 0);
}

// ---------------------------------------------------------------------------
// u cell layout (the key trick): u for logical (b, t, n, g) is stored in the
// 256-col slice at PHYSICAL row  R = b*8192 + ((t+1)&127)*64 + (n&~15) + nt'
// (nt' = g>>4), as a 1KB cell ordered [lane(q*16+c)][i(4)], where q=(n&15)>>2,
// i=n&3, c=g&15. rec wave w's 2 cells per step are rows +w*2, +w*2+1.
//  - GEMM epilogue: one dwordx4 store per acc tile -> 1KB contiguous.
//  - rec load: 2 dwordx4 per wave per step -> 1KB contiguous each.
//  - hazard: cell(s) lives in rows h-overwritten at step s+1 BY THE SAME
//    BLOCK; consume-wait(start of s) < barrier(s) < h-write(s+1). Sound.
//  - wrap: cell(127) lives in rows(0); preloaded before the initial
//    __syncthreads (full drain) -> precedes any h-write.
// ---------------------------------------------------------------------------

__global__ __launch_bounds__(256, 2) void gemm_u(
    const float* __restrict__ A, int ldA, int K,
    const float* __restrict__ W,
    const float* __restrict__ bias,
    float* __restrict__ outp, int outcol)
{
  __shared__ alignas(16) f16 Ah[4096];
  __shared__ alignas(16) f16 Al[4096];
  __shared__ alignas(16) f16 Bh[8192];
  __shared__ alignas(16) f16 Bl[8192];

  const int tid = threadIdx.x;
  const int w = tid >> 6, lane = tid & 63, q = lane >> 4, c = lane & 15;
  const int mbase = blockIdx.x * 128;
  const int seg = tid & 7, rbase = tid >> 3;

  float4v acc[2][16] = {};
  const int nchunk = K >> 5;

  float4v va[4], vb[8];
  #pragma unroll
  for (int it = 0; it < 4; ++it)
    va[it] = *(const float4v*)(A + (size_t)(mbase + it * 32 + rbase) * ldA + seg * 4);
  #pragma unroll
  for (int it = 0; it < 8; ++it)
    vb[it] = *(const float4v*)(W + (size_t)(it * 32 + rbase) * K + seg * 4);

  for (int kc = 0; kc < nchunk; ++kc) {
    #pragma unroll
    for (int it = 0; it < 4; ++it) {
      int row = it * 32 + rbase;
      float4v v = va[it];
      f16 h0 = (f16)v.x, h1 = (f16)v.y, h2 = (f16)v.z, h3 = (f16)v.w;
      half4 hi = {h0, h1, h2, h3};
      half4 lo = {(f16)(v.x - (float)h0), (f16)(v.y - (float)h1),
                  (f16)(v.z - (float)h2), (f16)(v.w - (float)h3)};
      int mt = row >> 4, m = row & 15, qq = seg >> 1, jj = (seg & 1) * 4;
      int ofs = ((mt * 4 + qq) * 16 + m) * 8 + jj;
      *(half4*)&Ah[ofs] = hi;
      *(half4*)&Al[ofs] = lo;
    }
    #pragma unroll
    for (int it = 0; it < 8; ++it) {
      int g = it * 32 + rbase;
      float4v v = vb[it];
      f16 h0 = (f16)v.x, h1 = (f16)v.y, h2 = (f16)v.z, h3 = (f16)v.w;
      half4 hi = {h0, h1, h2, h3};
      half4 lo = {(f16)(v.x - (float)h0), (f16)(v.y - (float)h1),
                  (f16)(v.z - (float)h2), (f16)(v.w - (float)h3)};
      int nt = g >> 4, n = g & 15, qq = seg >> 1, jj = (seg & 1) * 4;
      int ofs = ((nt * 4 + qq) * 16 + n) * 8 + jj;
      *(half4*)&Bh[ofs] = hi;
      *(half4*)&Bl[ofs] = lo;
    }
    __syncthreads();

    if (kc + 1 < nchunk) {
      int ko = (kc + 1) * 32;
      #pragma unroll
      for (int it = 0; it < 4; ++it)
        va[it] = *(const float4v*)(A + (size_t)(mbase + it * 32 + rbase) * ldA + ko + seg * 4);
      #pragma unroll
      for (int it = 0; it < 8; ++it)
        vb[it] = *(const float4v*)(W + (size_t)(it * 32 + rbase) * K + ko + seg * 4);
    }

    half8 ah[2], al[2];
    #pragma unroll
    for (int m2 = 0; m2 < 2; ++m2) {
      int mt = w * 2 + m2;
      int ofs = ((mt * 4 + q) * 16 + c) * 8;
      ah[m2] = *(half8*)&Ah[ofs];
      al[m2] = *(half8*)&Al[ofs];
    }
    #pragma unroll
    for (int nt = 0; nt < 16; ++nt) {
      int ofs = ((nt * 4 + q) * 16 + c) * 8;
      half8 bh = *(half8*)&Bh[ofs];
      half8 bl = *(half8*)&Bl[ofs];
      #pragma unroll
      for (int m2 = 0; m2 < 2; ++m2) {
        acc[m2][nt] = mfma16(ah[m2], bh, acc[m2][nt]);
        acc[m2][nt] = mfma16(al[m2], bh, acc[m2][nt]);
        acc[m2][nt] = mfma16(ah[m2], bl, acc[m2][nt]);
      }
    }
    __syncthreads();
  }

  // ---- epilogue: permuted-cell stores, 1KB contiguous dwordx4 per tile.
  // acc[m2][nt][i]: logical row = mbase + (w*2+m2)*16 + q*4+i, col = nt*16+c.
  #pragma unroll
  for (int m2 = 0; m2 < 2; ++m2) {
    const int m2t = w * 2 + m2;
    const int b_ = mbase >> 13;
    const int t_ = ((mbase >> 6) + (m2t >> 2)) & 127;
    const int n0 = (m2t & 3) * 16;
    const size_t rowbase =
        ((size_t)b_ * 8192 + (size_t)((t_ + 1) & 127) * 64 + n0) * 768
        + outcol + (q * 16 + c) * 4;
    #pragma unroll
    for (int nt = 0; nt < 16; ++nt) {
      const float bsv = bias[nt * 16 + c];
      float4v vst;
      vst.x = acc[m2][nt][0] + bsv;
      vst.y = acc[m2][nt][1] + bsv;
      vst.z = acc[m2][nt][2] + bsv;
      vst.w = acc[m2][nt][3] + bsv;
      *(float4v*)&outp[rowbase + (size_t)nt * 768] = vst;
    }
  }
}

// ---------------------------------------------------------------------------
// rec_layer v4: h_t = 0.1*h_{t-1} + 0.9*tanh(u_t + h_{t-1} @ W_hh^T)
// 32 blocks x 8 waves (2 waves/SIMD for latency hiding; per-wave work halved
// vs v3: 2 column-tiles each). W_hh B-frags in regs; h via double-buffered
// LDS in A-frag order; u loaded from permuted cells (2x dwordx4/wave/step)
// and folded into the MFMA accumulator init (cell layout == C layout);
// tanh via raw v_exp_f32 + v_rcp_f32:  hn = fma(-1.8, rcp(exp2(c*x)+1),
// fma(0.1,h,0.9))  -- ~9 VALU/elem vs ~19 with the libm divide.
// per-step sync = raw "s_waitcnt lgkmcnt(0); s_barrier" (no vmcnt drain:
// h-stores fire-and-forget, u-prefetch keeps a full step of latency cover).
// ---------------------------------------------------------------------------
__global__ __launch_bounds__(512, 1) void rec_layer(
    float* __restrict__ io, const float* __restrict__ whh, int outcol)
{
  __shared__ alignas(16) f16 hbuf[2][4096];  // [buf][kc(8)][quad(4)][m(16)][j(8)]

  const int tid = threadIdx.x;
  const int w = tid >> 6, lane = tid & 63, q = lane >> 4, c = lane & 15;
  const int r0 = blockIdx.x * 16;
  const int b_ = r0 >> 6, n0 = r0 & 63;

  // preload W_hh B-fragments: wf[tn][kc] -> B[k=kc*32+q*8+j][n=g], g=w*32+tn*16+c
  half8 wf[2][8];
  #pragma unroll
  for (int tn = 0; tn < 2; ++tn) {
    const int g = w * 32 + tn * 16 + c;
    #pragma unroll
    for (int kc = 0; kc < 8; ++kc) {
      const float* src = whh + (size_t)g * 256 + kc * 32 + q * 8;
      float4v v0 = *(const float4v*)src;
      float4v v1 = *(const float4v*)(src + 4);
      half8 h = {(f16)v0.x, (f16)v0.y, (f16)v0.z, (f16)v0.w,
                 (f16)v1.x, (f16)v1.y, (f16)v1.z, (f16)v1.w};
      wf[tn][kc] = h;
    }
  }

  // zero both h buffers (h0 = 0)
  {
    uint32_t* p = (uint32_t*)hbuf;
    #pragma unroll
    for (int i = 0; i < 8; ++i) p[tid + i * 512] = 0u;
  }

  float hreg[2][4] = {};     // persistent h in C layout (fp32)
  size_t base[4];            // h-store bases (final layout), t=0
  #pragma unroll
  for (int i = 0; i < 4; ++i) {
    const int r = r0 + q * 4 + i;
    base[i] = ((size_t)(r >> 6) * 8192 + (r & 63)) * 768 + outcol + w * 32 + c;
  }

  // u cell base for this (block, wave, lane): rows b*8192 + 0 + n0 + w*2+tn
  const size_t ucell0 =
      ((size_t)b_ * 8192 + n0 + w * 2) * 768 + outcol + (q * 16 + c) * 4;

  // preload cell(127) (@rows 0) and cell(0) (@rows 1)
  float4v uv127[2], uvc[2];
  #pragma unroll
  for (int tn = 0; tn < 2; ++tn)
    uv127[tn] = *(const float4v*)&io[ucell0 + (size_t)tn * 768];
  #pragma unroll
  for (int tn = 0; tn < 2; ++tn)
    uvc[tn] = *(const float4v*)&io[ucell0 + 49152 + (size_t)tn * 768];

  __syncthreads();   // full drain once; makes the rows(0) preload sound

  for (int t = 0; t < 128; ++t) {
    const f16* rb = hbuf[t & 1];
    f16* wb = hbuf[(t + 1) & 1];

    // A-fragments of h_{t-1} (conflict-free ds_read_b128)
    half8 af[8];
    #pragma unroll
    for (int kc = 0; kc < 8; ++kc)
      af[kc] = *(const half8*)&rb[((kc * 4 + q) * 16 + c) * 8];

    // prefetch u for step t+1 (cells @ rows(t+2)); t=126 -> have uv127
    float4v uvn[2];
    if (t < 126) {
      const size_t po = ucell0 + (size_t)(t + 2) * 49152;
      #pragma unroll
      for (int tn = 0; tn < 2; ++tn)
        uvn[tn] = *(const float4v*)&io[po + (size_t)tn * 768];
    }

    // rec = u_t + h_{t-1} @ W_hh^T : acc0 seeded with u (cell layout == C
    // layout by construction); 16 MFMAs, 4 chains of depth 4.
    float4v acc0[2], acc1[2];
    #pragma unroll
    for (int tn = 0; tn < 2; ++tn) {
      acc0[tn] = uvc[tn];
      acc1[tn] = (float4v){0.f, 0.f, 0.f, 0.f};
    }
    #pragma unroll
    for (int kc = 0; kc < 4; ++kc) {
      #pragma unroll
      for (int tn = 0; tn < 2; ++tn) {
        acc0[tn] = mfma16(af[kc], wf[tn][kc], acc0[tn]);
        acc1[tn] = mfma16(af[kc + 4], wf[tn][kc + 4], acc1[tn]);
      }
    }

    // tanh + blend; h -> global (fire-and-forget) + LDS A-layout for t+1
    const size_t sofs = (size_t)t * 49152;
    #pragma unroll
    for (int tn = 0; tn < 2; ++tn) {
      const int gcol = w * 32 + tn * 16 + c;
      const int widx = (((gcol >> 5) * 4 + ((gcol >> 3) & 3)) * 16) * 8 + (gcol & 7);
      #pragma unroll
      for (int i = 0; i < 4; ++i) {
        const float xv = acc0[tn][i] + acc1[tn][i];
        // tanh(x) = 1 - 2/(exp2(2*log2e*x)+1); rcp/exp2 are HW-approx (~1ulp)
        const float e  = __builtin_amdgcn_exp2f(xv * 2.8853900817779268f);
        const float rr = __builtin_amdgcn_rcpf(e + 1.0f);
        const float hn = fmaf(-1.8f, rr, fmaf(0.1f, hreg[tn][i], 0.9f));
        hreg[tn][i] = hn;
        io[base[i] + sofs + tn * 16] = hn;
        wb[widx + (q * 4 + i) * 8] = (f16)hn;
      }
    }

    if (t < 127) {
      // order LDS only; do NOT drain vmcnt (stores/prefetch stay in flight)
      asm volatile("s_waitcnt lgkmcnt(0)\n\ts_barrier" ::: "memory");
      #pragma unroll
      for (int tn = 0; tn < 2; ++tn)
        uvc[tn] = (t == 126) ? uv127[tn] : uvn[tn];
    }
  }
}

extern "C" void kernel_launch(void* const* d_in, const int* in_sizes, int n_in,
                              void* d_out, int out_size, void* d_ws, size_t ws_size,
                              hipStream_t stream) {
  (void)in_sizes; (void)n_in; (void)out_size; (void)d_ws; (void)ws_size;
  const float* x     = (const float*)d_in[0];   // [8,128,64,32]
  const float* w_ih0 = (const float*)d_in[1];   // [256,32]
  const float* w_ih  = (const float*)d_in[2];   // [2,256,256]
  const float* b_ih  = (const float*)d_in[3];   // [3,256]
  const float* w_hh  = (const float*)d_in[4];   // [3,256,256]
  float* out = (float*)d_out;                   // [8,128,64,768] fp32

  gemm_u<<<512, 256, 0, stream>>>(x,         32,  32, w_ih0,         b_ih,       out, 0);
  rec_layer<<<32, 512, 0, stream>>>(out, w_hh,            0);
  gemm_u<<<512, 256, 0, stream>>>(out,       768, 256, w_ih,          b_ih + 256, out, 256);
  rec_layer<<<32, 512, 0, stream>>>(out, w_hh + 65536,    256);
  gemm_u<<<512, 256, 0, stream>>>(out + 256, 768, 256, w_ih + 65536,  b_ih + 512, out, 512);
  rec_layer<<<32, 512, 0, stream>>>(out, w_hh + 131072,   512);
}

// Round 2
// 532.161 us; speedup vs baseline: 1.3971x; 1.0475x over previous
//
#include <hip/hip_runtime.h>
#include <cstdint>
#include <cstddef>

typedef _Float16 f16;
typedef _Float16 half8 __attribute__((ext_vector_type(8)));
typedef _Float16 half4 __attribute__((ext_vector_type(4)));
typedef float float4v __attribute__((ext_vector_type(4)));

static __device__ __forceinline__ float4v mfma16(half8 a, half8 b, float4v c) {
  return __builtin_amdgcn_mfma_f32_16x16x32_f16(a, b, c, 0, 0, 0);
}

// ---------------------------------------------------------------------------
// u cell layout (the key trick): u for logical (b, t, n, g) is stored in the
// 256-col slice at PHYSICAL row  R = b*8192 + ((t+1)&127)*64 + (n&~15) + nt'
// (nt' = g>>4), as a 1KB cell ordered [lane(q*16+c)][i(4)], where q=(n&15)>>2,
// i=n&3, c=g&15. rec wave w's cell per step is row +w.
//  - GEMM epilogue: one dwordx4 store per acc tile -> 1KB contiguous.
//  - rec load: 1 dwordx4 per wave per step -> 1KB contiguous.
//  - hazard: cell(s) lives in rows h-overwritten at step s+1 BY THE SAME
//    BLOCK; load(s-1) < vmcnt-wait/consume(s) < barrier(s) < h-write(s+1).
//  - wrap: cell(127) lives in rows(0); preloaded before the initial
//    __syncthreads (full drain) -> precedes any h-write.
// ---------------------------------------------------------------------------

__global__ __launch_bounds__(256, 2) void gemm_u(
    const float* __restrict__ A, int ldA, int K,
    const float* __restrict__ W,
    const float* __restrict__ bias,
    float* __restrict__ outp, int outcol)
{
  __shared__ alignas(16) f16 Ah[4096];
  __shared__ alignas(16) f16 Al[4096];
  __shared__ alignas(16) f16 Bh[8192];
  __shared__ alignas(16) f16 Bl[8192];

  const int tid = threadIdx.x;
  const int w = tid >> 6, lane = tid & 63, q = lane >> 4, c = lane & 15;
  const int mbase = blockIdx.x * 128;
  const int seg = tid & 7, rbase = tid >> 3;

  float4v acc[2][16] = {};
  const int nchunk = K >> 5;

  float4v va[4], vb[8];
  #pragma unroll
  for (int it = 0; it < 4; ++it)
    va[it] = *(const float4v*)(A + (size_t)(mbase + it * 32 + rbase) * ldA + seg * 4);
  #pragma unroll
  for (int it = 0; it < 8; ++it)
    vb[it] = *(const float4v*)(W + (size_t)(it * 32 + rbase) * K + seg * 4);

  for (int kc = 0; kc < nchunk; ++kc) {
    #pragma unroll
    for (int it = 0; it < 4; ++it) {
      int row = it * 32 + rbase;
      float4v v = va[it];
      f16 h0 = (f16)v.x, h1 = (f16)v.y, h2 = (f16)v.z, h3 = (f16)v.w;
      half4 hi = {h0, h1, h2, h3};
      half4 lo = {(f16)(v.x - (float)h0), (f16)(v.y - (float)h1),
                  (f16)(v.z - (float)h2), (f16)(v.w - (float)h3)};
      int mt = row >> 4, m = row & 15, qq = seg >> 1, jj = (seg & 1) * 4;
      int ofs = ((mt * 4 + qq) * 16 + m) * 8 + jj;
      *(half4*)&Ah[ofs] = hi;
      *(half4*)&Al[ofs] = lo;
    }
    #pragma unroll
    for (int it = 0; it < 8; ++it) {
      int g = it * 32 + rbase;
      float4v v = vb[it];
      f16 h0 = (f16)v.x, h1 = (f16)v.y, h2 = (f16)v.z, h3 = (f16)v.w;
      half4 hi = {h0, h1, h2, h3};
      half4 lo = {(f16)(v.x - (float)h0), (f16)(v.y - (float)h1),
                  (f16)(v.z - (float)h2), (f16)(v.w - (float)h3)};
      int nt = g >> 4, n = g & 15, qq = seg >> 1, jj = (seg & 1) * 4;
      int ofs = ((nt * 4 + qq) * 16 + n) * 8 + jj;
      *(half4*)&Bh[ofs] = hi;
      *(half4*)&Bl[ofs] = lo;
    }
    __syncthreads();

    if (kc + 1 < nchunk) {
      int ko = (kc + 1) * 32;
      #pragma unroll
      for (int it = 0; it < 4; ++it)
        va[it] = *(const float4v*)(A + (size_t)(mbase + it * 32 + rbase) * ldA + ko + seg * 4);
      #pragma unroll
      for (int it = 0; it < 8; ++it)
        vb[it] = *(const float4v*)(W + (size_t)(it * 32 + rbase) * K + ko + seg * 4);
    }

    half8 ah[2], al[2];
    #pragma unroll
    for (int m2 = 0; m2 < 2; ++m2) {
      int mt = w * 2 + m2;
      int ofs = ((mt * 4 + q) * 16 + c) * 8;
      ah[m2] = *(half8*)&Ah[ofs];
      al[m2] = *(half8*)&Al[ofs];
    }
    #pragma unroll
    for (int nt = 0; nt < 16; ++nt) {
      int ofs = ((nt * 4 + q) * 16 + c) * 8;
      half8 bh = *(half8*)&Bh[ofs];
      half8 bl = *(half8*)&Bl[ofs];
      #pragma unroll
      for (int m2 = 0; m2 < 2; ++m2) {
        acc[m2][nt] = mfma16(ah[m2], bh, acc[m2][nt]);
        acc[m2][nt] = mfma16(al[m2], bh, acc[m2][nt]);
        acc[m2][nt] = mfma16(ah[m2], bl, acc[m2][nt]);
      }
    }
    __syncthreads();
  }

  // ---- epilogue: permuted-cell stores, 1KB contiguous dwordx4 per tile.
  // acc[m2][nt][i]: logical row = mbase + (w*2+m2)*16 + q*4+i, col = nt*16+c.
  #pragma unroll
  for (int m2 = 0; m2 < 2; ++m2) {
    const int m2t = w * 2 + m2;
    const int b_ = mbase >> 13;
    const int t_ = ((mbase >> 6) + (m2t >> 2)) & 127;
    const int n0 = (m2t & 3) * 16;
    const size_t rowbase =
        ((size_t)b_ * 8192 + (size_t)((t_ + 1) & 127) * 64 + n0) * 768
        + outcol + (q * 16 + c) * 4;
    #pragma unroll
    for (int nt = 0; nt < 16; ++nt) {
      const float bsv = bias[nt * 16 + c];
      float4v vst;
      vst.x = acc[m2][nt][0] + bsv;
      vst.y = acc[m2][nt][1] + bsv;
      vst.z = acc[m2][nt][2] + bsv;
      vst.w = acc[m2][nt][3] + bsv;
      *(float4v*)&outp[rowbase + (size_t)nt * 768] = vst;
    }
  }
}

// ---------------------------------------------------------------------------
// rec_layer v5: h_t = 0.1*h_{t-1} + 0.9*tanh(u_t + h_{t-1} @ W_hh^T)
// 32 blocks x 16 waves (4 waves/SIMD -> 4-way latency-chain interleave;
// per-wave work halved vs v4: 1 column-tile of 16 cols each). W_hh B-frags
// in regs; h via double-buffered LDS in A-frag order; u loaded from permuted
// cells (1x dwordx4/wave/step) and folded into the MFMA accumulator init
// (cell layout == C layout by construction); tanh via raw v_exp_f32 +
// v_rcp_f32:  hn = fma(-1.8, rcp(exp2(c*x)+1), fma(0.1,h,0.9)).
// per-step sync = raw "s_waitcnt lgkmcnt(0); s_barrier" (no vmcnt drain:
// h-stores fire-and-forget, u-prefetch keeps a full step of latency cover).
// ---------------------------------------------------------------------------
__global__ __launch_bounds__(1024, 1) void rec_layer(
    float* __restrict__ io, const float* __restrict__ whh, int outcol)
{
  __shared__ alignas(16) f16 hbuf[2][4096];  // [buf][kc(8)][quad(4)][m(16)][j(8)]

  const int tid = threadIdx.x;
  const int w = tid >> 6, lane = tid & 63, q = lane >> 4, c = lane & 15;
  const int r0 = blockIdx.x * 16;
  const int b_ = r0 >> 6, n0 = r0 & 63;

  // preload W_hh B-fragments: wf[kc] -> B[k=kc*32+q*8+j][n=g], g=w*16+c
  half8 wf[8];
  {
    const int g = w * 16 + c;
    #pragma unroll
    for (int kc = 0; kc < 8; ++kc) {
      const float* src = whh + (size_t)g * 256 + kc * 32 + q * 8;
      float4v v0 = *(const float4v*)src;
      float4v v1 = *(const float4v*)(src + 4);
      half8 h = {(f16)v0.x, (f16)v0.y, (f16)v0.z, (f16)v0.w,
                 (f16)v1.x, (f16)v1.y, (f16)v1.z, (f16)v1.w};
      wf[kc] = h;
    }
  }

  // zero both h buffers (h0 = 0); 16384 B = 4096 dwords, 1024 threads
  {
    uint32_t* p = (uint32_t*)hbuf;
    #pragma unroll
    for (int i = 0; i < 4; ++i) p[tid + i * 1024] = 0u;
  }

  float hreg[4] = {};        // persistent h in C layout (fp32)
  size_t base[4];            // h-store bases (final layout), t=0
  #pragma unroll
  for (int i = 0; i < 4; ++i) {
    const int r = r0 + q * 4 + i;
    base[i] = ((size_t)(r >> 6) * 8192 + (r & 63)) * 768 + outcol + w * 16 + c;
  }

  // u cell base for this (block, wave, lane): row b*8192 + 0 + n0 + w
  const size_t ucell0 =
      ((size_t)b_ * 8192 + n0 + w) * 768 + outcol + (q * 16 + c) * 4;

  // preload cell(127) (@rows 0) and cell(0) (@rows 1)
  float4v uv127, uvc;
  uv127 = *(const float4v*)&io[ucell0];
  uvc   = *(const float4v*)&io[ucell0 + 49152];

  __syncthreads();   // full drain once; makes the rows(0) preload sound

  for (int t = 0; t < 128; ++t) {
    const f16* rb = hbuf[t & 1];
    f16* wb = hbuf[(t + 1) & 1];

    // A-fragments of h_{t-1} (conflict-free ds_read_b128)
    half8 af[8];
    #pragma unroll
    for (int kc = 0; kc < 8; ++kc)
      af[kc] = *(const half8*)&rb[((kc * 4 + q) * 16 + c) * 8];

    // prefetch u for step t+1 (cell @ rows(t+2)); t=126 -> have uv127
    float4v uvn;
    if (t < 126)
      uvn = *(const float4v*)&io[ucell0 + (size_t)(t + 2) * 49152];

    // rec = u_t + h_{t-1} @ W_hh^T : acc0 seeded with u (cell layout == C
    // layout by construction); 8 MFMAs, 2 chains of depth 4.
    float4v acc0 = uvc;
    float4v acc1 = (float4v){0.f, 0.f, 0.f, 0.f};
    #pragma unroll
    for (int kc = 0; kc < 4; ++kc) {
      acc0 = mfma16(af[kc], wf[kc], acc0);
      acc1 = mfma16(af[kc + 4], wf[kc + 4], acc1);
    }

    // tanh + blend; h -> global (fire-and-forget) + LDS A-layout for t+1
    const size_t sofs = (size_t)t * 49152;
    const int gcol = w * 16 + c;
    const int widx = (((gcol >> 5) * 4 + ((gcol >> 3) & 3)) * 16) * 8 + (gcol & 7);
    #pragma unroll
    for (int i = 0; i < 4; ++i) {
      const float xv = acc0[i] + acc1[i];
      // tanh(x) = 1 - 2/(exp2(2*log2e*x)+1); rcp/exp2 are HW-approx (~1ulp)
      const float e  = __builtin_amdgcn_exp2f(xv * 2.8853900817779268f);
      const float rr = __builtin_amdgcn_rcpf(e + 1.0f);
      const float hn = fmaf(-1.8f, rr, fmaf(0.1f, hreg[i], 0.9f));
      hreg[i] = hn;
      io[base[i] + sofs] = hn;
      wb[widx + (q * 4 + i) * 8] = (f16)hn;
    }

    if (t < 127) {
      // order LDS only; do NOT drain vmcnt (stores/prefetch stay in flight)
      asm volatile("s_waitcnt lgkmcnt(0)\n\ts_barrier" ::: "memory");
      uvc = (t == 126) ? uv127 : uvn;
    }
  }
}

extern "C" void kernel_launch(void* const* d_in, const int* in_sizes, int n_in,
                              void* d_out, int out_size, void* d_ws, size_t ws_size,
                              hipStream_t stream) {
  (void)in_sizes; (void)n_in; (void)out_size; (void)d_ws; (void)ws_size;
  const float* x     = (const float*)d_in[0];   // [8,128,64,32]
  const float* w_ih0 = (const float*)d_in[1];   // [256,32]
  const float* w_ih  = (const float*)d_in[2];   // [2,256,256]
  const float* b_ih  = (const float*)d_in[3];   // [3,256]
  const float* w_hh  = (const float*)d_in[4];   // [3,256,256]
  float* out = (float*)d_out;                   // [8,128,64,768] fp32

  gemm_u<<<512, 256, 0, stream>>>(x,         32,  32, w_ih0,         b_ih,       out, 0);
  rec_layer<<<32, 1024, 0, stream>>>(out, w_hh,            0);
  gemm_u<<<512, 256, 0, stream>>>(out,       768, 256, w_ih,          b_ih + 256, out, 256);
  rec_layer<<<32, 1024, 0, stream>>>(out, w_hh + 65536,    256);
  gemm_u<<<512, 256, 0, stream>>>(out + 256, 768, 256, w_ih + 65536,  b_ih + 512, out, 512);
  rec_layer<<<32, 1024, 0, stream>>>(out, w_hh + 131072,   512);
}